// Round 4
// baseline (136.636 us; speedup 1.0000x reference)
//
#include <hip/hip_runtime.h>
#include <math.h>

#define NN 4096
#define DD 512
#define MARGINF 1.0f
#define NCLS 64
#define MAXM 160
#define TRI (MAXM * (MAXM - 1) / 2)   // 12720

typedef __attribute__((ext_vector_type(8))) short bf16x8;  // 8 bf16 (4 VGPRs)
typedef __attribute__((ext_vector_type(4))) float f32x4;   // 4 fp32 acc

// ws layout (float indices):
#define WS_SQ   0         // float[4096] ||x_i||^2
#define WS_NS   4096      // float[4096] neg_sum          (memset 0)
#define WS_LOSS 8192      // float[1]                      (memset 0)
#define WS_CTR  8193      // uint[1] pair2 completion ctr  (memset 0)
#define WS_CNT  8256      // int[64] class counts          (memset 0)
#define WS_RK   8320      // int[4096] rank within class
#define WS_MEM  12416     // int[64*160] class member lists
#define WS_XB   32768     // ushort[4096*512] bf16 X (4 MB)
#define WS_PD   1081344   // float[64*TRI] positive-pair distances

__device__ __forceinline__ unsigned short f2bf(float f) {
    unsigned u = __float_as_uint(f);
    u += 0x7fffu + ((u >> 16) & 1u);   // round-to-nearest-even
    return (unsigned short)(u >> 16);
}

__device__ __forceinline__ void gl_lds16(const void* g, void* l) {
    __builtin_amdgcn_global_load_lds(
        (__attribute__((address_space(1))) unsigned int*)g,
        (__attribute__((address_space(3))) unsigned int*)l,
        16, 0, 0);
}

// Fused: row norms + bf16 conversion + class build (counts pre-zeroed by memset).
__global__ __launch_bounds__(256) void prep_kernel(const float* __restrict__ X,
                                                   const int* __restrict__ tgt,
                                                   float* __restrict__ ws) {
    const int wv = threadIdx.x >> 6, lane = threadIdx.x & 63;
    const int row = blockIdx.x * 4 + wv;
    const float4* xr = (const float4*)(X + (size_t)row * DD);
    float4 a = xr[lane], b = xr[lane + 64];
    float s = a.x * a.x + a.y * a.y + a.z * a.z + a.w * a.w
            + b.x * b.x + b.y * b.y + b.z * b.z + b.w * b.w;
#pragma unroll
    for (int off = 32; off; off >>= 1) s += __shfl_down(s, off, 64);
    if (lane == 0) {
        ws[WS_SQ + row] = s;
        int c = tgt[row];
        int p = atomicAdd(&((int*)(ws + WS_CNT))[c], 1);
        ((int*)(ws + WS_RK))[row] = p;
        if (p < MAXM) ((int*)(ws + WS_MEM))[c * MAXM + p] = row;
    }
    ushort4 pa = {f2bf(a.x), f2bf(a.y), f2bf(a.z), f2bf(a.w)};
    ushort4 pb = {f2bf(b.x), f2bf(b.y), f2bf(b.z), f2bf(b.w)};
    ushort4* xb = (ushort4*)((unsigned short*)(ws + WS_XB) + (size_t)row * DD);
    xb[lane] = pa;
    xb[lane + 64] = pb;
}

// Gram via bf16 MFMA: 128x128 tile, BK=32, 8 waves (each 32x64), LDS
// double-buffered with ONE barrier per K-iter. Triangular grid (bi<=bj).
__global__ __launch_bounds__(512, 2) void negsum_kernel(const int* __restrict__ tgt,
                                                        float* __restrict__ ws) {
    __shared__ unsigned short As[2][128 * 32];
    __shared__ unsigned short Bs[2][128 * 32];

    const int bidx = blockIdx.x;
    int bj = (int)((sqrtf(8.0f * (float)bidx + 1.0f) - 1.0f) * 0.5f);
    while (bj * (bj + 1) / 2 > bidx) --bj;
    while ((bj + 1) * (bj + 2) / 2 <= bidx) ++bj;
    const int bi = bidx - bj * (bj + 1) / 2;   // bi <= bj
    const int i0 = bi * 128, j0 = bj * 128;

    const int tid = threadIdx.x;
    const int w = tid >> 6, lane = tid & 63;
    const unsigned short* Xb = (const unsigned short*)(ws + WS_XB);

    // staging: wave w loads rows w*16..w*16+15 (1 KB each of A and B per iter)
    const unsigned short* gA = Xb + (size_t)(i0 + w * 16 + (lane >> 2)) * DD + (lane & 3) * 8;
    const unsigned short* gB = Xb + (size_t)(j0 + w * 16 + (lane >> 2)) * DD + (lane & 3) * 8;

    const int m_ = lane & 15, q = lane >> 4;
    const int wr = (w & 3) * 32;    // 4 row groups of 32
    const int wc = (w >> 2) * 64;   // 2 col groups of 64

    f32x4 acc[2][4] = {};

    gl_lds16(gA, As[0] + w * 512);   // prologue: stage buf 0
    gl_lds16(gB, Bs[0] + w * 512);

    for (int it = 0; it < 16; ++it) {
        const int buf = it & 1;
        __syncthreads();   // drains vmcnt(0): buf is ready; prev readers done w/ buf^1
        if (it + 1 < 16) {
            gl_lds16(gA + (it + 1) * 32, As[buf ^ 1] + w * 512);
            gl_lds16(gB + (it + 1) * 32, Bs[buf ^ 1] + w * 512);
        }
        bf16x8 af[2], bfr[4];
#pragma unroll
        for (int u = 0; u < 2; ++u)
            af[u] = *(const bf16x8*)(As[buf] + (wr + u * 16 + m_) * 32 + q * 8);
#pragma unroll
        for (int v = 0; v < 4; ++v)
            bfr[v] = *(const bf16x8*)(Bs[buf] + (wc + v * 16 + m_) * 32 + q * 8);
#pragma unroll
        for (int u = 0; u < 2; ++u)
#pragma unroll
            for (int v = 0; v < 4; ++v)
                acc[u][v] = __builtin_amdgcn_mfma_f32_16x16x32_bf16(
                    af[u], bfr[v], acc[u][v], 0, 0, 0);
    }

    // epilogue: C/D map col=lane&15, row=(lane>>4)*4+reg
    const float* sq = ws + WS_SQ;
    float* ns = ws + WS_NS;
    const int* rk = (const int*)(ws + WS_RK);
    float* posd = ws + WS_PD;
    float sjv[4]; int tjv[4], jv[4];
#pragma unroll
    for (int v = 0; v < 4; ++v) {
        int j = j0 + wc + v * 16 + m_;
        jv[v] = j;
        sjv[v] = sq[j];
        tjv[v] = tgt[j];
    }
    float colp[4] = {0.0f, 0.0f, 0.0f, 0.0f};
#pragma unroll
    for (int u = 0; u < 2; ++u) {
#pragma unroll
        for (int r = 0; r < 4; ++r) {
            const int i = i0 + wr + u * 16 + q * 4 + r;
            const float si = sq[i];
            const int ti = tgt[i];
            float rp = 0.0f;
#pragma unroll
            for (int v = 0; v < 4; ++v) {
                float d2 = si + sjv[v] - 2.0f * acc[u][v][r];
                float dist = d2 > 0.0f ? sqrtf(d2) : 0.0f;
                if (tjv[v] != ti) {
                    float e = __expf(MARGINF - dist);
                    rp += e;
                    colp[v] += e;
                } else if (i < jv[v]) {
                    int ra = rk[i], rb = rk[jv[v]];
                    if (ra < MAXM && rb < MAXM) {
                        int hi = ra > rb ? ra : rb;
                        int lo = ra > rb ? rb : ra;
                        posd[ti * TRI + hi * (hi - 1) / 2 + lo] = dist;
                    }
                }
            }
            rp += __shfl_xor(rp, 1, 64);
            rp += __shfl_xor(rp, 2, 64);
            rp += __shfl_xor(rp, 4, 64);
            rp += __shfl_xor(rp, 8, 64);
            if (m_ == 0) atomicAdd(&ns[i], rp);
        }
    }
    if (bi != bj) {   // symmetric contribution: G[j][i] == G[i][j]
#pragma unroll
        for (int v = 0; v < 4; ++v) {
            float cp = colp[v];
            cp += __shfl_xor(cp, 16, 64);
            cp += __shfl_xor(cp, 32, 64);
            if (q == 0) atomicAdd(&ns[jv[v]], cp);
        }
    }
}

// Positive pairs from stored distances; last block finalizes the mean.
__global__ __launch_bounds__(256) void pair2_kernel(float* __restrict__ ws,
                                                    float* __restrict__ out) {
    __shared__ float wsum[4];
    __shared__ bool last;
    const int c = blockIdx.x;
    const int tid = threadIdx.x;
    int mc = ((const int*)(ws + WS_CNT))[c];
    if (mc > MAXM) mc = MAXM;
    const int P = mc * (mc - 1) / 2;
    const int* mem = (const int*)(ws + WS_MEM) + c * MAXM;
    const float* pd = ws + WS_PD + c * TRI;
    const float* ns = ws + WS_NS;
    float lsum = 0.0f;
    for (int p = tid; p < P; p += 256) {
        int b = (int)((1.0f + sqrtf(1.0f + 8.0f * (float)p)) * 0.5f);
        while (b * (b - 1) / 2 > p) --b;
        while ((b + 1) * b / 2 <= p) ++b;
        const int a = p - b * (b - 1) / 2;
        const float dist = pd[b * (b - 1) / 2 + a];
        const int i = mem[a], j = mem[b];
        float J = __logf(ns[i] + ns[j]) + dist;
        float h = fmaxf(J, 0.0f);
        lsum += h * h;
    }
#pragma unroll
    for (int off = 32; off; off >>= 1) lsum += __shfl_xor(lsum, off, 64);
    const int wv = tid >> 6, lane = tid & 63;
    if (lane == 0) wsum[wv] = lsum;
    __syncthreads();
    if (tid == 0) {
        float s = wsum[0] + wsum[1] + wsum[2] + wsum[3];
        if (s != 0.0f) atomicAdd(&ws[WS_LOSS], s);
        __threadfence();
        unsigned d = atomicAdd((unsigned*)&ws[WS_CTR], 1u);
        last = (d == NCLS - 1);
    }
    __syncthreads();
    if (last && tid < 64) {
        int mcv = ((const int*)(ws + WS_CNT))[tid];
        float lp = (float)(mcv * (mcv - 1));
#pragma unroll
        for (int off = 32; off; off >>= 1) lp += __shfl_down(lp, off, 64);
        if (tid == 0) {
            float total = atomicAdd(&ws[WS_LOSS], 0.0f);  // device-scope read
            out[0] = total / lp;
        }
    }
}

extern "C" void kernel_launch(void* const* d_in, const int* in_sizes, int n_in,
                              void* d_out, int out_size, void* d_ws, size_t ws_size,
                              hipStream_t stream) {
    const float* X  = (const float*)d_in[0];
    const int*  tgt = (const int*)d_in[1];
    float* ws  = (float*)d_ws;
    float* out = (float*)d_out;

    // zero ns + loss + ctr + counts in one shot (floats [4096, 8320))
    hipMemsetAsync(ws + WS_NS, 0, (8320 - 4096) * sizeof(float), stream);
    hipLaunchKernelGGL(prep_kernel, dim3(NN / 4), dim3(256), 0, stream, X, tgt, ws);
    hipLaunchKernelGGL(negsum_kernel, dim3(528), dim3(512), 0, stream, tgt, ws);
    hipLaunchKernelGGL(pair2_kernel, dim3(NCLS), dim3(256), 0, stream, ws, out);
}

// Round 5
// 119.661 us; speedup vs baseline: 1.1419x; 1.1419x over previous
//
#include <hip/hip_runtime.h>
#include <math.h>

#define NN 4096
#define DD 512
#define MARGINF 1.0f
#define NCLS 64
#define MAXM 160
#define TRI (MAXM * (MAXM - 1) / 2)   // 12720
#define NBLK 2080                     // 64*65/2 triangular 64-tiles

typedef __attribute__((ext_vector_type(8))) short bf16x8;  // 8 bf16 (4 VGPRs)
typedef __attribute__((ext_vector_type(4))) float f32x4;   // 4 fp32 acc

// ws layout (float indices):
#define WS_SQ   0         // float[4096] ||x_i||^2
#define WS_NS   4096      // float[4096] neg_sum
#define WS_LOSS 8192      // float[1] sum hinge^2
#define WS_CNT  8256      // int[64] class counts
#define WS_RK   8320      // int[4096] rank within class
#define WS_MEM  12416     // int[64*160] class member lists
#define WS_XB   32768     // ushort[4096*512] bf16 X (4 MB)
#define WS_PD   1081344   // float[64*TRI] positive-pair distances

__device__ __forceinline__ unsigned short f2bf(float f) {
    unsigned u = __float_as_uint(f);
    u += 0x7fffu + ((u >> 16) & 1u);   // round-to-nearest-even
    return (unsigned short)(u >> 16);
}

__device__ __forceinline__ void gl_lds16(const void* g, void* l) {
    __builtin_amdgcn_global_load_lds(
        (__attribute__((address_space(1))) unsigned int*)g,
        (__attribute__((address_space(3))) unsigned int*)l,
        16, 0, 0);
}

// Row norms + bf16 conversion + zero-init. One wave per row.
__global__ __launch_bounds__(256) void prep_kernel(const float* __restrict__ X,
                                                   float* __restrict__ ws) {
    const int wv = threadIdx.x >> 6, lane = threadIdx.x & 63;
    const int row = blockIdx.x * 4 + wv;
    const float4* xr = (const float4*)(X + (size_t)row * DD);
    float4 a = xr[lane], b = xr[lane + 64];
    float s = a.x * a.x + a.y * a.y + a.z * a.z + a.w * a.w
            + b.x * b.x + b.y * b.y + b.z * b.z + b.w * b.w;
#pragma unroll
    for (int off = 32; off; off >>= 1) s += __shfl_down(s, off, 64);
    if (lane == 0) { ws[WS_SQ + row] = s; ws[WS_NS + row] = 0.0f; }
    ushort4 pa = {f2bf(a.x), f2bf(a.y), f2bf(a.z), f2bf(a.w)};
    ushort4 pb = {f2bf(b.x), f2bf(b.y), f2bf(b.z), f2bf(b.w)};
    ushort4* xb = (ushort4*)((unsigned short*)(ws + WS_XB) + (size_t)row * DD);
    xb[lane] = pa;
    xb[lane + 64] = pb;
    if (blockIdx.x == 0) {
        if (threadIdx.x < NCLS) ((int*)(ws + WS_CNT))[threadIdx.x] = 0;
        if (threadIdx.x == 0) ws[WS_LOSS] = 0.0f;
    }
}

__global__ __launch_bounds__(256) void class_build_kernel(const int* __restrict__ tgt,
                                                          float* __restrict__ ws) {
    const int t = blockIdx.x * 256 + threadIdx.x;
    const int c = tgt[t];
    int p = atomicAdd(&((int*)(ws + WS_CNT))[c], 1);
    ((int*)(ws + WS_RK))[t] = p;
    if (p < MAXM) ((int*)(ws + WS_MEM))[c * MAXM + p] = t;
}

// Gram via bf16 MFMA: 64x64 tile, BK=32, 4 waves each 32x32, triangular grid
// (2080 blocks = 8.1/CU for occupancy). XOR-swizzled LDS layout: chunk q of
// row r stored at slot (q + (r>>1))&3 -> 2-way read conflicts (free).
// Swizzle applied on the GLOBAL FETCH side so gl_lds16's lane-contiguous
// LDS write pattern is preserved.
__global__ __launch_bounds__(256, 8) void negsum_kernel(const int* __restrict__ tgt,
                                                        float* __restrict__ ws) {
    __shared__ unsigned short As[64 * 32];   // 4 KB
    __shared__ unsigned short Bs[64 * 32];   // 4 KB

    const int bidx = blockIdx.x;
    int bj = (int)((sqrtf(8.0f * (float)bidx + 1.0f) - 1.0f) * 0.5f);
    while (bj * (bj + 1) / 2 > bidx) --bj;
    while ((bj + 1) * (bj + 2) / 2 <= bidx) ++bj;
    const int bi = bidx - bj * (bj + 1) / 2;   // bi <= bj
    const int i0 = bi * 64, j0 = bj * 64;

    const int tid = threadIdx.x;
    const int w = tid >> 6, lane = tid & 63;
    const unsigned short* Xb = (const unsigned short*)(ws + WS_XB);

    // staging: wave w loads rows w*16..w*16+15 of both tiles (1 KB each).
    // lane l covers (row = w*16 + (l>>2), slot s = l&3); fetches global
    // chunk c = (s - (row>>1))&3 = ((l&3) - (l>>3))&3  [w*16>>1 ≡ 0 mod 4]
    const int srow = w * 16 + (lane >> 2);
    const int sc = (((lane & 3) - (lane >> 3)) & 3) * 8;
    const unsigned short* gA = Xb + (size_t)(i0 + srow) * DD + sc;
    const unsigned short* gB = Xb + (size_t)(j0 + srow) * DD + sc;
    unsigned short* lA = As + w * 512;   // wave-uniform LDS base
    unsigned short* lB = Bs + w * 512;

    const int m_ = lane & 15, q = lane >> 4;
    const int wr = (w & 1) * 32, wc = (w >> 1) * 32;
    // reader swizzle: slot = (q + (m_>>1))&3   [wr,u*16 ≡ 0 mod 8]
    const int sl = ((q + (m_ >> 1)) & 3) * 8;

    f32x4 acc[2][2] = {};

    for (int it = 0; it < 16; ++it) {
        __syncthreads();                       // prev readers done
        gl_lds16(gA + it * 32, lA);
        gl_lds16(gB + it * 32, lB);
        __syncthreads();                       // vmcnt(0) drains before barrier
        bf16x8 af[2], bfr[2];
#pragma unroll
        for (int u = 0; u < 2; ++u)
            af[u] = *(const bf16x8*)(As + (wr + u * 16 + m_) * 32 + sl);
#pragma unroll
        for (int v = 0; v < 2; ++v)
            bfr[v] = *(const bf16x8*)(Bs + (wc + v * 16 + m_) * 32 + sl);
#pragma unroll
        for (int u = 0; u < 2; ++u)
#pragma unroll
            for (int v = 0; v < 2; ++v)
                acc[u][v] = __builtin_amdgcn_mfma_f32_16x16x32_bf16(
                    af[u], bfr[v], acc[u][v], 0, 0, 0);
    }

    // epilogue: C/D map col=lane&15, row=(lane>>4)*4+reg
    const float* sq = ws + WS_SQ;
    float* ns = ws + WS_NS;
    const int* rk = (const int*)(ws + WS_RK);
    float* posd = ws + WS_PD;
    float sjv[2]; int tjv[2], jv[2];
#pragma unroll
    for (int v = 0; v < 2; ++v) {
        int j = j0 + wc + v * 16 + m_;
        jv[v] = j;
        sjv[v] = sq[j];
        tjv[v] = tgt[j];
    }
    float colp[2] = {0.0f, 0.0f};
#pragma unroll
    for (int u = 0; u < 2; ++u) {
#pragma unroll
        for (int r = 0; r < 4; ++r) {
            const int i = i0 + wr + u * 16 + q * 4 + r;
            const float si = sq[i];
            const int ti = tgt[i];
            float rp = 0.0f;
#pragma unroll
            for (int v = 0; v < 2; ++v) {
                float d2 = si + sjv[v] - 2.0f * acc[u][v][r];
                float dist = d2 > 0.0f ? sqrtf(d2) : 0.0f;
                if (tjv[v] != ti) {
                    float e = __expf(MARGINF - dist);
                    rp += e;
                    colp[v] += e;
                } else if (i < jv[v]) {
                    int ra = rk[i], rb = rk[jv[v]];
                    if (ra < MAXM && rb < MAXM) {
                        int hi = ra > rb ? ra : rb;
                        int lo = ra > rb ? rb : ra;
                        posd[ti * TRI + hi * (hi - 1) / 2 + lo] = dist;
                    }
                }
            }
            rp += __shfl_xor(rp, 1, 64);
            rp += __shfl_xor(rp, 2, 64);
            rp += __shfl_xor(rp, 4, 64);
            rp += __shfl_xor(rp, 8, 64);
            if (m_ == 0) atomicAdd(&ns[i], rp);
        }
    }
    if (bi != bj) {   // symmetric contribution: G[j][i] == G[i][j]
#pragma unroll
        for (int v = 0; v < 2; ++v) {
            float cp = colp[v];
            cp += __shfl_xor(cp, 16, 64);
            cp += __shfl_xor(cp, 32, 64);
            if (q == 0) atomicAdd(&ns[jv[v]], cp);
        }
    }
}

// Positive pairs from stored distances.
__global__ __launch_bounds__(256) void pair2_kernel(float* __restrict__ ws) {
    __shared__ float wsum[4];
    const int c = blockIdx.x;
    int mc = ((const int*)(ws + WS_CNT))[c];
    if (mc > MAXM) mc = MAXM;
    const int P = mc * (mc - 1) / 2;
    const int* mem = (const int*)(ws + WS_MEM) + c * MAXM;
    const float* pd = ws + WS_PD + c * TRI;
    const float* ns = ws + WS_NS;
    float lsum = 0.0f;
    for (int p = threadIdx.x; p < P; p += 256) {
        int b = (int)((1.0f + sqrtf(1.0f + 8.0f * (float)p)) * 0.5f);
        while (b * (b - 1) / 2 > p) --b;
        while ((b + 1) * b / 2 <= p) ++b;
        const int a = p - b * (b - 1) / 2;
        const float dist = pd[b * (b - 1) / 2 + a];
        const int i = mem[a], j = mem[b];
        float J = __logf(ns[i] + ns[j]) + dist;
        float h = fmaxf(J, 0.0f);
        lsum += h * h;
    }
#pragma unroll
    for (int off = 32; off; off >>= 1) lsum += __shfl_xor(lsum, off, 64);
    const int wv = threadIdx.x >> 6, lane = threadIdx.x & 63;
    if (lane == 0) wsum[wv] = lsum;
    __syncthreads();
    if (threadIdx.x == 0) {
        float s = wsum[0] + wsum[1] + wsum[2] + wsum[3];
        if (s != 0.0f) atomicAdd(&ws[WS_LOSS], s);
    }
}

__global__ void finalize_kernel(const float* __restrict__ ws, float* __restrict__ out) {
    const int t = threadIdx.x;
    int mcv = (t < NCLS) ? ((const int*)(ws + WS_CNT))[t] : 0;
    float lp = (float)(mcv * (mcv - 1));
#pragma unroll
    for (int off = 32; off; off >>= 1) lp += __shfl_down(lp, off, 64);
    if (t == 0) out[0] = ws[WS_LOSS] / lp;
}

extern "C" void kernel_launch(void* const* d_in, const int* in_sizes, int n_in,
                              void* d_out, int out_size, void* d_ws, size_t ws_size,
                              hipStream_t stream) {
    const float* X  = (const float*)d_in[0];
    const int*  tgt = (const int*)d_in[1];
    float* ws  = (float*)d_ws;
    float* out = (float*)d_out;

    hipLaunchKernelGGL(prep_kernel, dim3(NN / 4), dim3(256), 0, stream, X, ws);
    hipLaunchKernelGGL(class_build_kernel, dim3(NN / 256), dim3(256), 0, stream, tgt, ws);
    hipLaunchKernelGGL(negsum_kernel, dim3(NBLK), dim3(256), 0, stream, tgt, ws);
    hipLaunchKernelGGL(pair2_kernel, dim3(NCLS), dim3(256), 0, stream, ws);
    hipLaunchKernelGGL(finalize_kernel, dim3(1), dim3(64), 0, stream, ws, out);
}